// Round 7
// baseline (304.981 us; speedup 1.0000x reference)
//
#include <hip/hip_runtime.h>
#include <hip/hip_fp16.h>
#include <math.h>

#define BB 32
#define NN 1024
#define MM 1024
#define FF 64
#define INF_ 1e30f

typedef float f32x4 __attribute__((ext_vector_type(4)));

// ---------------- norms: one wave per row (x and y concatenated) --------------
__global__ __launch_bounds__(256) void norms_kernel(const float* __restrict__ x,
                                                    const float* __restrict__ y,
                                                    float* __restrict__ xn,
                                                    float* __restrict__ yn) {
    int gw = (blockIdx.x * 256 + threadIdx.x) >> 6;   // global wave = row index
    int lane = threadIdx.x & 63;
    int total = BB * NN + BB * MM;
    if (gw >= total) return;
    const float* src; float* dst; int row;
    if (gw < BB * NN) { src = x; dst = xn; row = gw; }
    else             { src = y; dst = yn; row = gw - BB * NN; }
    float v = src[(size_t)row * FF + lane];
    float s = v * v;
    #pragma unroll
    for (int d = 32; d > 0; d >>= 1) s += __shfl_xor(s, d, 64);
    if (lane == 0) dst[row] = s;
}

// ------- cost: 64x64 tile per 256-thread block; SHEARED fp16 store ------------
// costD[((row+col)&1023)*MM + row] = (half)cost[row][col]
__global__ __launch_bounds__(256) void cost_kernel(const float* __restrict__ x,
                                                   const float* __restrict__ y,
                                                   const float* __restrict__ xn,
                                                   const float* __restrict__ yn,
                                                   __half* __restrict__ cost) {
    __shared__ float Xs[FF][68];   // [k][row], padded
    __shared__ float Ys[FF][68];
    const int b    = blockIdx.z;
    const int row0 = blockIdx.y * 64;
    const int col0 = blockIdx.x * 64;
    const int tid  = threadIdx.x;
    const float* xb = x + (size_t)b * NN * FF;
    const float* yb = y + (size_t)b * MM * FF;

    #pragma unroll
    for (int cc = 0; cc < 4; ++cc) {
        int s  = tid + cc * 256;      // 0..1023 float4 slots
        int r  = s >> 4;              // tile row 0..63
        int kq = s & 15;              // k-quad 0..15
        float4 vx = *(const float4*)(xb + (size_t)(row0 + r) * FF + kq * 4);
        float4 vy = *(const float4*)(yb + (size_t)(col0 + r) * FF + kq * 4);
        Xs[kq*4+0][r] = vx.x; Xs[kq*4+1][r] = vx.y; Xs[kq*4+2][r] = vx.z; Xs[kq*4+3][r] = vx.w;
        Ys[kq*4+0][r] = vy.x; Ys[kq*4+1][r] = vy.y; Ys[kq*4+2][r] = vy.z; Ys[kq*4+3][r] = vy.w;
    }
    __syncthreads();

    const int tx = tid & 15, ty = tid >> 4;
    float acc[4][4] = {};
    #pragma unroll 16
    for (int k = 0; k < FF; ++k) {
        float4 a  = *(const float4*)&Xs[k][ty * 4];
        float4 bb = *(const float4*)&Ys[k][tx * 4];
        float av[4] = {a.x, a.y, a.z, a.w};
        float bv[4] = {bb.x, bb.y, bb.z, bb.w};
        #pragma unroll
        for (int r = 0; r < 4; ++r)
            #pragma unroll
            for (int c = 0; c < 4; ++c)
                acc[r][c] += av[r] * bv[c];
    }

    __half* cD = cost + (size_t)b * NN * MM;
    #pragma unroll
    for (int r = 0; r < 4; ++r) {
        int row = row0 + ty * 4 + r;
        float xnv = xn[b * NN + row];
        #pragma unroll
        for (int c = 0; c < 4; ++c) {
            int col = col0 + tx * 4 + c;
            float v = xnv + yn[b * MM + col] - 2.0f * acc[r][c];
            v = sqrtf(fmaxf(v, 0.0f));
            cD[(size_t)((row + col) & 1023) * MM + row] = __float2half(v);
        }
    }
}

// ---------------- DPP shift (gfx9 encoding, live on gfx950) -------------------
__device__ __forceinline__ float dpp_wave_shr1(float v, float oldv) {
    // lane i <- lane i-1; lane 0 <- oldv  (bound_ctrl=false keeps old)
    int t = __builtin_amdgcn_update_dpp(__float_as_int(oldv), __float_as_int(v),
                                        0x138, 0xf, 0xf, false);
    return __int_as_float(t);
}

// ---------------- fp16 diag row buffer, asm-issued loads ----------------------
struct RowBufH { f32x4 q0, q1; };   // raw 8 dwords = 16 halfs

__device__ __forceinline__ void issue_rowh(RowBufH& R, const __half* rowbase,
                                           unsigned voff) {
    asm volatile(
        "global_load_dwordx4 %0, %2, %3\n\t"
        "global_load_dwordx4 %1, %2, %3 offset:16"
        : "=v"(R.q0), "=v"(R.q1)
        : "v"(voff), "s"(rowbase));
}

__device__ __forceinline__ void unpack16(const RowBufH& R, float cc[16]) {
    #pragma unroll
    for (int q = 0; q < 4; ++q) {
        unsigned w0 = __float_as_uint(R.q0[q]);
        unsigned w1 = __float_as_uint(R.q1[q]);
        __half2 h0 = *reinterpret_cast<__half2*>(&w0);
        __half2 h1 = *reinterpret_cast<__half2*>(&w1);
        cc[2*q+0]   = __low2float(h0);  cc[2*q+1]   = __high2float(h0);
        cc[8+2*q+0] = __low2float(h1);  cc[8+2*q+1] = __high2float(h1);
    }
}

// ---------------- DTW DP over anti-diagonals: one wave per batch --------------
// lane l owns rows i in [16l, 16l+16). At diagonal d, slot i computes cell
// (i, d-i):  cur[i] = c[i] + min(prev[i], prev[i-1], prev2[i-1]).
// Invalid slots self-pin at ~1e30; stale slots are never read by valid cells.
__global__ __launch_bounds__(64, 1) void dtw_diag_kernel(const __half* __restrict__ cost,
                                                         float* __restrict__ out) {
    const int b    = blockIdx.x;
    const int lane = threadIdx.x;
    const __half* cbD = cost + (size_t)b * NN * MM;   // uniform across wave
    const unsigned voff = (unsigned)lane * 32u;       // 16 halfs/lane

    RowBufH R0, R1, R2, R3, R4, R5, R6, R7, R8, R9, R10, R11, R12, R13, R14, R15;
    issue_rowh(R0,  cbD +  0 * (size_t)MM, voff);
    issue_rowh(R1,  cbD +  1 * (size_t)MM, voff);
    issue_rowh(R2,  cbD +  2 * (size_t)MM, voff);
    issue_rowh(R3,  cbD +  3 * (size_t)MM, voff);
    issue_rowh(R4,  cbD +  4 * (size_t)MM, voff);
    issue_rowh(R5,  cbD +  5 * (size_t)MM, voff);
    issue_rowh(R6,  cbD +  6 * (size_t)MM, voff);
    issue_rowh(R7,  cbD +  7 * (size_t)MM, voff);
    issue_rowh(R8,  cbD +  8 * (size_t)MM, voff);
    issue_rowh(R9,  cbD +  9 * (size_t)MM, voff);
    issue_rowh(R10, cbD + 10 * (size_t)MM, voff);
    issue_rowh(R11, cbD + 11 * (size_t)MM, voff);
    issue_rowh(R12, cbD + 12 * (size_t)MM, voff);
    issue_rowh(R13, cbD + 13 * (size_t)MM, voff);
    issue_rowh(R14, cbD + 14 * (size_t)MM, voff);
    issue_rowh(R15, cbD + 15 * (size_t)MM, voff);

    float A[16], B[16];
    #pragma unroll
    for (int j = 0; j < 16; ++j) { A[j] = INF_; B[j] = INF_; }
    float bnd = 0.0f;    // diag-neighbor injected at (0,0) only; INF_ afterwards

    // one diagonal: wait oldest row (32 loads in flight, FIFO), compute, reissue
    #define DIAG_STEP(Rk, PV, P2, NR)                                          \
    {                                                                          \
        asm volatile("s_waitcnt vmcnt(30)" ::: "memory");                      \
        __builtin_amdgcn_sched_barrier(0);                                     \
        float cc[16]; unpack16(Rk, cc);                                        \
        float pvm1 = dpp_wave_shr1(PV[15], INF_);                              \
        float p2m1 = dpp_wave_shr1(P2[15], bnd);                               \
        _Pragma("unroll")                                                      \
        for (int r = 0; r < 16; ++r) {                                         \
            float pv_r = PV[r], p2_r = P2[r];                                  \
            P2[r] = cc[r] + fminf(fminf(pv_r, pvm1), p2m1);                    \
            pvm1 = pv_r; p2m1 = p2_r;                                          \
        }                                                                      \
        __builtin_amdgcn_sched_barrier(0);                                     \
        issue_rowh(Rk, cbD + (size_t)(NR) * MM, voff);                         \
    }

    // peel first 16 diagonals (d = 0..15); bnd -> INF_ after d = 0
    DIAG_STEP(R0,  A, B, 16)   bnd = INF_;
    DIAG_STEP(R1,  B, A, 17)
    DIAG_STEP(R2,  A, B, 18)
    DIAG_STEP(R3,  B, A, 19)
    DIAG_STEP(R4,  A, B, 20)
    DIAG_STEP(R5,  B, A, 21)
    DIAG_STEP(R6,  A, B, 22)
    DIAG_STEP(R7,  B, A, 23)
    DIAG_STEP(R8,  A, B, 24)
    DIAG_STEP(R9,  B, A, 25)
    DIAG_STEP(R10, A, B, 26)
    DIAG_STEP(R11, B, A, 27)
    DIAG_STEP(R12, A, B, 28)
    DIAG_STEP(R13, B, A, 29)
    DIAG_STEP(R14, A, B, 30)
    DIAG_STEP(R15, B, A, 31)

    for (int d0 = 16; d0 < 2032; d0 += 16) {
        DIAG_STEP(R0,  A, B, ((d0 + 16) & 1023))
        DIAG_STEP(R1,  B, A, ((d0 + 17) & 1023))
        DIAG_STEP(R2,  A, B, ((d0 + 18) & 1023))
        DIAG_STEP(R3,  B, A, ((d0 + 19) & 1023))
        DIAG_STEP(R4,  A, B, ((d0 + 20) & 1023))
        DIAG_STEP(R5,  B, A, ((d0 + 21) & 1023))
        DIAG_STEP(R6,  A, B, ((d0 + 22) & 1023))
        DIAG_STEP(R7,  B, A, ((d0 + 23) & 1023))
        DIAG_STEP(R8,  A, B, ((d0 + 24) & 1023))
        DIAG_STEP(R9,  B, A, ((d0 + 25) & 1023))
        DIAG_STEP(R10, A, B, ((d0 + 26) & 1023))
        DIAG_STEP(R11, B, A, ((d0 + 27) & 1023))
        DIAG_STEP(R12, A, B, ((d0 + 28) & 1023))
        DIAG_STEP(R13, B, A, ((d0 + 29) & 1023))
        DIAG_STEP(R14, A, B, ((d0 + 30) & 1023))
        DIAG_STEP(R15, B, A, ((d0 + 31) & 1023))
    }

    // tail: d = 2032..2046 (15 steps; reissues are dummies, keep vmcnt invariant)
    DIAG_STEP(R0,  A, B, 0)
    DIAG_STEP(R1,  B, A, 1)
    DIAG_STEP(R2,  A, B, 2)
    DIAG_STEP(R3,  B, A, 3)
    DIAG_STEP(R4,  A, B, 4)
    DIAG_STEP(R5,  B, A, 5)
    DIAG_STEP(R6,  A, B, 6)
    DIAG_STEP(R7,  B, A, 7)
    DIAG_STEP(R8,  A, B, 8)
    DIAG_STEP(R9,  B, A, 9)
    DIAG_STEP(R10, A, B, 10)
    DIAG_STEP(R11, B, A, 11)
    DIAG_STEP(R12, A, B, 12)
    DIAG_STEP(R13, B, A, 13)
    DIAG_STEP(R14, A, B, 14)   // d = 2046 writes B; D(1023,1023) = B[15]@lane63
    #undef DIAG_STEP

    if (lane == 63) out[b] = B[15];
}

// ---------------- fused fallback (no workspace): cost on the fly --------------
__global__ __launch_bounds__(1024) void dtw_fused_kernel(const float* __restrict__ x,
                                                         const float* __restrict__ y,
                                                         float* __restrict__ out) {
    const int b    = blockIdx.x;
    const int tid  = threadIdx.x;
    const int lane = tid & 63;
    const int wid  = tid >> 6;
    __shared__ float P[MM];
    __shared__ float xrow[FF];
    __shared__ float part_sum[16];
    __shared__ float part_min[16];

    float yr[FF];
    const float* yrow = y + ((size_t)b * MM + tid) * FF;
    #pragma unroll
    for (int q = 0; q < FF / 4; ++q) {
        float4 v = ((const float4*)yrow)[q];
        yr[q*4+0] = v.x; yr[q*4+1] = v.y; yr[q*4+2] = v.z; yr[q*4+3] = v.w;
    }

    P[tid] = INF_;
    __syncthreads();

    const float* xb = x + (size_t)b * NN * FF;
    float result = 0.0f;

    for (int i = 0; i < NN; ++i) {
        if (tid < FF) xrow[tid] = xb[(size_t)i * FF + tid];
        float up   = P[tid];
        float diag = (tid == 0) ? (i == 0 ? 0.0f : INF_) : P[tid - 1];
        float m    = fminf(up, diag);
        __syncthreads();

        float ss = 0.0f;
        #pragma unroll 16
        for (int k = 0; k < FF; ++k) {
            float d = xrow[k] - yr[k];
            ss += d * d;
        }
        float c = sqrtf(ss);

        float s = c;
        #pragma unroll
        for (int d = 1; d < 64; d <<= 1) {
            float t = __shfl_up(s, d, 64);
            if (lane >= d) s += t;
        }
        if (lane == 63) part_sum[wid] = s;
        __syncthreads();
        if (tid < 16) {
            float p = part_sum[tid];
            #pragma unroll
            for (int d = 1; d < 16; d <<= 1) {
                float t = __shfl_up(p, d, 64);
                if (tid >= d) p += t;
            }
            part_sum[tid] = p;
        }
        __syncthreads();
        float C = s + (wid > 0 ? part_sum[wid - 1] : 0.0f);

        float z = c + m - C;
        float w = z;
        #pragma unroll
        for (int d = 1; d < 64; d <<= 1) {
            float t = __shfl_up(w, d, 64);
            if (lane >= d) w = fminf(w, t);
        }
        if (lane == 63) part_min[wid] = w;
        __syncthreads();
        if (tid < 16) {
            float p = part_min[tid];
            #pragma unroll
            for (int d = 1; d < 16; d <<= 1) {
                float t = __shfl_up(p, d, 64);
                if (tid >= d) p = fminf(p, t);
            }
            part_min[tid] = p;
        }
        __syncthreads();
        float wm  = (wid > 0) ? fminf(w, part_min[wid - 1]) : w;
        float cur = C + wm;

        P[tid] = cur;
        __syncthreads();
        if (i == NN - 1 && tid == MM - 1) result = cur;
    }
    if (tid == MM - 1) out[b] = result;
}

extern "C" void kernel_launch(void* const* d_in, const int* in_sizes, int n_in,
                              void* d_out, int out_size, void* d_ws, size_t ws_size,
                              hipStream_t stream) {
    const float* x = (const float*)d_in[0];
    const float* y = (const float*)d_in[1];
    float* out = (float*)d_out;

    size_t cost_bytes = (size_t)BB * NN * MM * sizeof(__half);
    size_t need = cost_bytes
                + (size_t)BB * NN * sizeof(float)
                + (size_t)BB * MM * sizeof(float);

    if (ws_size >= need) {
        __half* cost = (__half*)d_ws;
        float* xn = (float*)((char*)d_ws + cost_bytes);
        float* yn = xn + (size_t)BB * NN;

        int total_rows = BB * NN + BB * MM;
        int blocks = (total_rows + 3) / 4;
        hipLaunchKernelGGL(norms_kernel, dim3(blocks), dim3(256), 0, stream,
                           x, y, xn, yn);
        hipLaunchKernelGGL(cost_kernel, dim3(MM / 64, NN / 64, BB), dim3(256), 0, stream,
                           x, y, xn, yn, cost);
        hipLaunchKernelGGL(dtw_diag_kernel, dim3(BB), dim3(64), 0, stream, cost, out);
    } else {
        hipLaunchKernelGGL(dtw_fused_kernel, dim3(BB), dim3(1024), 0, stream, x, y, out);
    }
}

// Round 9
// 263.712 us; speedup vs baseline: 1.1565x; 1.1565x over previous
//
#include <hip/hip_runtime.h>
#include <math.h>

#define BB 32
#define NN 1024
#define MM 1024
#define FF 64
#define INF_ 1e30f

typedef float f32x4 __attribute__((ext_vector_type(4)));

// ---------------- norms: one wave per row (x and y concatenated) --------------
__global__ __launch_bounds__(256) void norms_kernel(const float* __restrict__ x,
                                                    const float* __restrict__ y,
                                                    float* __restrict__ xn,
                                                    float* __restrict__ yn) {
    int gw = (blockIdx.x * 256 + threadIdx.x) >> 6;   // global wave = row index
    int lane = threadIdx.x & 63;
    int total = BB * NN + BB * MM;
    if (gw >= total) return;
    const float* src; float* dst; int row;
    if (gw < BB * NN) { src = x; dst = xn; row = gw; }
    else             { src = y; dst = yn; row = gw - BB * NN; }
    float v = src[(size_t)row * FF + lane];
    float s = v * v;
    #pragma unroll
    for (int d = 32; d > 0; d >>= 1) s += __shfl_xor(s, d, 64);
    if (lane == 0) dst[row] = s;
}

// ------- cost: 64x64 tile per 256-thread block; SHEARED fp32 store ------------
// costD[((row+col)&1023)*MM + row] = cost[row][col]  (bijective, same 4MB/batch)
__global__ __launch_bounds__(256) void cost_kernel(const float* __restrict__ x,
                                                   const float* __restrict__ y,
                                                   const float* __restrict__ xn,
                                                   const float* __restrict__ yn,
                                                   float* __restrict__ cost) {
    __shared__ float Xs[FF][68];   // [k][row], padded
    __shared__ float Ys[FF][68];
    const int b    = blockIdx.z;
    const int row0 = blockIdx.y * 64;
    const int col0 = blockIdx.x * 64;
    const int tid  = threadIdx.x;
    const float* xb = x + (size_t)b * NN * FF;
    const float* yb = y + (size_t)b * MM * FF;

    #pragma unroll
    for (int cc = 0; cc < 4; ++cc) {
        int s  = tid + cc * 256;      // 0..1023 float4 slots
        int r  = s >> 4;              // tile row 0..63
        int kq = s & 15;              // k-quad 0..15
        float4 vx = *(const float4*)(xb + (size_t)(row0 + r) * FF + kq * 4);
        float4 vy = *(const float4*)(yb + (size_t)(col0 + r) * FF + kq * 4);
        Xs[kq*4+0][r] = vx.x; Xs[kq*4+1][r] = vx.y; Xs[kq*4+2][r] = vx.z; Xs[kq*4+3][r] = vx.w;
        Ys[kq*4+0][r] = vy.x; Ys[kq*4+1][r] = vy.y; Ys[kq*4+2][r] = vy.z; Ys[kq*4+3][r] = vy.w;
    }
    __syncthreads();

    const int tx = tid & 15, ty = tid >> 4;
    float acc[4][4] = {};
    #pragma unroll 16
    for (int k = 0; k < FF; ++k) {
        float4 a  = *(const float4*)&Xs[k][ty * 4];
        float4 bb = *(const float4*)&Ys[k][tx * 4];
        float av[4] = {a.x, a.y, a.z, a.w};
        float bv[4] = {bb.x, bb.y, bb.z, bb.w};
        #pragma unroll
        for (int r = 0; r < 4; ++r)
            #pragma unroll
            for (int c = 0; c < 4; ++c)
                acc[r][c] += av[r] * bv[c];
    }

    float* cD = cost + (size_t)b * NN * MM;
    #pragma unroll
    for (int r = 0; r < 4; ++r) {
        int row = row0 + ty * 4 + r;
        float xnv = xn[b * NN + row];
        #pragma unroll
        for (int c = 0; c < 4; ++c) {
            int col = col0 + tx * 4 + c;
            float v = xnv + yn[b * MM + col] - 2.0f * acc[r][c];
            v = sqrtf(fmaxf(v, 0.0f));
            cD[(size_t)((row + col) & 1023) * MM + row] = v;   // sheared
        }
    }
}

// ---------------- DPP shift (gfx9 encoding, live on gfx950) -------------------
__device__ __forceinline__ float dpp_wave_shr1(float v, float oldv) {
    // lane i <- lane i-1; lane 0 <- oldv  (bound_ctrl=false keeps old)
    int t = __builtin_amdgcn_update_dpp(__float_as_int(oldv), __float_as_int(v),
                                        0x138, 0xf, 0xf, false);
    return __int_as_float(t);
}

// ---------------- register diag buffer, asm-issued loads ----------------------
struct RowBuf { f32x4 q0, q1, q2, q3; };

__device__ __forceinline__ void issue_row(RowBuf& R, const float* rowbase,
                                          unsigned voff) {
    asm volatile(
        "global_load_dwordx4 %0, %4, %5\n\t"
        "global_load_dwordx4 %1, %4, %5 offset:16\n\t"
        "global_load_dwordx4 %2, %4, %5 offset:32\n\t"
        "global_load_dwordx4 %3, %4, %5 offset:48"
        : "=v"(R.q0), "=v"(R.q1), "=v"(R.q2), "=v"(R.q3)
        : "v"(voff), "s"(rowbase));
}

// ---------------- DTW DP over anti-diagonals: one wave per batch --------------
// lane l owns rows i in [16l, 16l+16). At diagonal d, slot i computes cell
// (i, d-i):  cur[i] = c[i] + min(prev[i], prev[i-1], prev2[i-1]).
// Invalid slots self-pin at ~1e30; stale slots are never read by valid cells.
// 8-row fp32 register ring: 32 loads in flight (vmcnt counter max is 63 —
// R8's 64-in-flight overflowed the 6-bit counter and broke FIFO accounting).
// amdgpu_waves_per_eu(1,1): structurally 1 wave/SIMD -> claim the full 512-VGPR
// budget so the ring is register-resident, not bounced through scratch.
__global__ __launch_bounds__(64)
__attribute__((amdgpu_waves_per_eu(1, 1)))
void dtw_diag_kernel(const float* __restrict__ cost, float* __restrict__ out) {
    const int b    = blockIdx.x;
    const int lane = threadIdx.x;
    const float* cbD = cost + (size_t)b * NN * MM;    // uniform across wave
    const unsigned voff = (unsigned)lane * 64u;       // 16 floats/lane

    RowBuf R0, R1, R2, R3, R4, R5, R6, R7;
    issue_row(R0, cbD + 0 * (size_t)MM, voff);
    issue_row(R1, cbD + 1 * (size_t)MM, voff);
    issue_row(R2, cbD + 2 * (size_t)MM, voff);
    issue_row(R3, cbD + 3 * (size_t)MM, voff);
    issue_row(R4, cbD + 4 * (size_t)MM, voff);
    issue_row(R5, cbD + 5 * (size_t)MM, voff);
    issue_row(R6, cbD + 6 * (size_t)MM, voff);
    issue_row(R7, cbD + 7 * (size_t)MM, voff);

    float A[16], B[16];
    #pragma unroll
    for (int j = 0; j < 16; ++j) { A[j] = INF_; B[j] = INF_; }
    float bnd = 0.0f;    // diag-neighbor injected at (0,0) only; INF_ afterwards

    // one diagonal: wait oldest buffer, compute, reissue (NR always valid row)
    #define DIAG_STEP(Rk, PV, P2, NR)                                          \
    {                                                                          \
        asm volatile("s_waitcnt vmcnt(28)" ::: "memory");                      \
        __builtin_amdgcn_sched_barrier(0);                                     \
        float cc[16] = {Rk.q0[0], Rk.q0[1], Rk.q0[2], Rk.q0[3],                \
                        Rk.q1[0], Rk.q1[1], Rk.q1[2], Rk.q1[3],                \
                        Rk.q2[0], Rk.q2[1], Rk.q2[2], Rk.q2[3],                \
                        Rk.q3[0], Rk.q3[1], Rk.q3[2], Rk.q3[3]};               \
        float pvm1 = dpp_wave_shr1(PV[15], INF_);                              \
        float p2m1 = dpp_wave_shr1(P2[15], bnd);                               \
        _Pragma("unroll")                                                      \
        for (int r = 0; r < 16; ++r) {                                         \
            float pv_r = PV[r], p2_r = P2[r];                                  \
            P2[r] = cc[r] + fminf(fminf(pv_r, pvm1), p2m1);                    \
            pvm1 = pv_r; p2m1 = p2_r;                                          \
        }                                                                      \
        __builtin_amdgcn_sched_barrier(0);                                     \
        issue_row(Rk, cbD + (size_t)(NR) * MM, voff);                          \
    }

    // peel first 8 diagonals (d = 0..7); bnd -> INF_ after d = 0
    DIAG_STEP(R0, A, B, 8)   bnd = INF_;
    DIAG_STEP(R1, B, A, 9)
    DIAG_STEP(R2, A, B, 10)
    DIAG_STEP(R3, B, A, 11)
    DIAG_STEP(R4, A, B, 12)
    DIAG_STEP(R5, B, A, 13)
    DIAG_STEP(R6, A, B, 14)
    DIAG_STEP(R7, B, A, 15)

    for (int d0 = 8; d0 < 2040; d0 += 8) {
        DIAG_STEP(R0, A, B, ((d0 +  8) & 1023))
        DIAG_STEP(R1, B, A, ((d0 +  9) & 1023))
        DIAG_STEP(R2, A, B, ((d0 + 10) & 1023))
        DIAG_STEP(R3, B, A, ((d0 + 11) & 1023))
        DIAG_STEP(R4, A, B, ((d0 + 12) & 1023))
        DIAG_STEP(R5, B, A, ((d0 + 13) & 1023))
        DIAG_STEP(R6, A, B, ((d0 + 14) & 1023))
        DIAG_STEP(R7, B, A, ((d0 + 15) & 1023))
    }

    // tail: d = 2040..2046 (reissued rows are dummies, keeps vmcnt invariant)
    DIAG_STEP(R0, A, B, 0)
    DIAG_STEP(R1, B, A, 1)
    DIAG_STEP(R2, A, B, 2)
    DIAG_STEP(R3, B, A, 3)
    DIAG_STEP(R4, A, B, 4)
    DIAG_STEP(R5, B, A, 5)
    DIAG_STEP(R6, A, B, 6)          // d = 2046 writes B; D(1023,1023) = B[15]@lane63
    #undef DIAG_STEP

    if (lane == 63) out[b] = B[15];
}

// ---------------- fused fallback (no workspace): cost on the fly --------------
__global__ __launch_bounds__(1024) void dtw_fused_kernel(const float* __restrict__ x,
                                                         const float* __restrict__ y,
                                                         float* __restrict__ out) {
    const int b    = blockIdx.x;
    const int tid  = threadIdx.x;
    const int lane = tid & 63;
    const int wid  = tid >> 6;
    __shared__ float P[MM];
    __shared__ float xrow[FF];
    __shared__ float part_sum[16];
    __shared__ float part_min[16];

    float yr[FF];
    const float* yrow = y + ((size_t)b * MM + tid) * FF;
    #pragma unroll
    for (int q = 0; q < FF / 4; ++q) {
        float4 v = ((const float4*)yrow)[q];
        yr[q*4+0] = v.x; yr[q*4+1] = v.y; yr[q*4+2] = v.z; yr[q*4+3] = v.w;
    }

    P[tid] = INF_;
    __syncthreads();

    const float* xb = x + (size_t)b * NN * FF;
    float result = 0.0f;

    for (int i = 0; i < NN; ++i) {
        if (tid < FF) xrow[tid] = xb[(size_t)i * FF + tid];
        float up   = P[tid];
        float diag = (tid == 0) ? (i == 0 ? 0.0f : INF_) : P[tid - 1];
        float m    = fminf(up, diag);
        __syncthreads();

        float ss = 0.0f;
        #pragma unroll 16
        for (int k = 0; k < FF; ++k) {
            float d = xrow[k] - yr[k];
            ss += d * d;
        }
        float c = sqrtf(ss);

        float s = c;
        #pragma unroll
        for (int d = 1; d < 64; d <<= 1) {
            float t = __shfl_up(s, d, 64);
            if (lane >= d) s += t;
        }
        if (lane == 63) part_sum[wid] = s;
        __syncthreads();
        if (tid < 16) {
            float p = part_sum[tid];
            #pragma unroll
            for (int d = 1; d < 16; d <<= 1) {
                float t = __shfl_up(p, d, 64);
                if (tid >= d) p += t;
            }
            part_sum[tid] = p;
        }
        __syncthreads();
        float C = s + (wid > 0 ? part_sum[wid - 1] : 0.0f);

        float z = c + m - C;
        float w = z;
        #pragma unroll
        for (int d = 1; d < 64; d <<= 1) {
            float t = __shfl_up(w, d, 64);
            if (lane >= d) w = fminf(w, t);
        }
        if (lane == 63) part_min[wid] = w;
        __syncthreads();
        if (tid < 16) {
            float p = part_min[tid];
            #pragma unroll
            for (int d = 1; d < 16; d <<= 1) {
                float t = __shfl_up(p, d, 64);
                if (tid >= d) p = fminf(p, t);
            }
            part_min[tid] = p;
        }
        __syncthreads();
        float wm  = (wid > 0) ? fminf(w, part_min[wid - 1]) : w;
        float cur = C + wm;

        P[tid] = cur;
        __syncthreads();
        if (i == NN - 1 && tid == MM - 1) result = cur;
    }
    if (tid == MM - 1) out[b] = result;
}

extern "C" void kernel_launch(void* const* d_in, const int* in_sizes, int n_in,
                              void* d_out, int out_size, void* d_ws, size_t ws_size,
                              hipStream_t stream) {
    const float* x = (const float*)d_in[0];
    const float* y = (const float*)d_in[1];
    float* out = (float*)d_out;

    size_t need = (size_t)BB * NN * MM * sizeof(float)
                + (size_t)BB * NN * sizeof(float)
                + (size_t)BB * MM * sizeof(float);

    if (ws_size >= need) {
        float* cost = (float*)d_ws;
        float* xn = cost + (size_t)BB * NN * MM;
        float* yn = xn + (size_t)BB * NN;

        int total_rows = BB * NN + BB * MM;
        int blocks = (total_rows + 3) / 4;
        hipLaunchKernelGGL(norms_kernel, dim3(blocks), dim3(256), 0, stream,
                           x, y, xn, yn);
        hipLaunchKernelGGL(cost_kernel, dim3(MM / 64, NN / 64, BB), dim3(256), 0, stream,
                           x, y, xn, yn, cost);
        hipLaunchKernelGGL(dtw_diag_kernel, dim3(BB), dim3(64), 0, stream, cost, out);
    } else {
        hipLaunchKernelGGL(dtw_fused_kernel, dim3(BB), dim3(1024), 0, stream, x, y, out);
    }
}